// Round 6
// baseline (433.227 us; speedup 1.0000x reference)
//
#include <hip/hip_runtime.h>
#include <hip/hip_bf16.h>

// CausalSelfAttention: B=4 T=2048 C=1024 H=16 D=64
// Pipeline: cvt(x) ; transpose-cvt(w_qkv,w_proj) ; GEMM1(x@Wqkv -> Q,K,Vt scatter)
//           flash-attn ; GEMM2(attn@Wproj -> fp32 out)
// Workspace usage: ~92.3 MB (5x 16.78MB + 6.3MB + 2.1MB)

typedef unsigned short us;
typedef short bf16x8 __attribute__((ext_vector_type(8)));
typedef float f32x4 __attribute__((ext_vector_type(4)));
typedef unsigned short us8 __attribute__((ext_vector_type(8)));

__device__ __forceinline__ us f2bf(float f) {
  union { float f; unsigned u; } v; v.f = f;
  unsigned r = v.u + 0x7fff + ((v.u >> 16) & 1);   // round-to-nearest-even
  return (us)(r >> 16);
}

// ---------- fp32 -> bf16, vectorized ----------
__global__ __launch_bounds__(256) void k_cvt(const float* __restrict__ in,
                                             us* __restrict__ out, int n) {
  int i = (blockIdx.x * blockDim.x + threadIdx.x) * 4;
  if (i >= n) return;
  float4 v = *reinterpret_cast<const float4*>(in + i);
  ushort4 o;
  o.x = f2bf(v.x); o.y = f2bf(v.y); o.z = f2bf(v.z); o.w = f2bf(v.w);
  *reinterpret_cast<ushort4*>(out + i) = o;
}

// ---------- transpose-convert: in [R][C] fp32 -> out [C][R] bf16 ----------
__global__ __launch_bounds__(256) void k_tc(const float* __restrict__ in,
                                            us* __restrict__ out, int R, int C) {
  __shared__ float tile[32][33];
  int c0 = blockIdx.x * 32, r0 = blockIdx.y * 32;
  int tx = threadIdx.x, ty = threadIdx.y;          // block (32,8)
  for (int j = 0; j < 32; j += 8)
    tile[ty + j][tx] = in[(size_t)(r0 + ty + j) * C + c0 + tx];
  __syncthreads();
  for (int j = 0; j < 32; j += 8)
    out[(size_t)(c0 + ty + j) * R + r0 + tx] = f2bf(tile[tx][ty + j]);
}

// ---------- bf16 GEMM: A[M][K] * Bt[N][K]^T.  EPI=0: fp32 C.  EPI=1: QKV scatter ----------
// 128x128 tile, BK=64, 256 thr = 4 waves (2x2), each wave 64x64 = 4x4 frags of 16x16x32.
template<int EPI>
__global__ __launch_bounds__(256) void k_gemm(
    const us* __restrict__ A, const us* __restrict__ Bt,
    float* __restrict__ Cf,
    us* __restrict__ Qb, us* __restrict__ Kb, us* __restrict__ Vt,
    int M, int N, int K)
{
  __shared__ us As[128][72];   // +8 pad: 144B row stride -> 2-way conflicts only
  __shared__ us Bs[128][72];
  int t = threadIdx.x;
  int lane = t & 63, w = t >> 6;
  int wm = (w >> 1) * 64, wn = (w & 1) * 64;
  int fr = lane & 15, fq = lane >> 4;
  int m0 = blockIdx.y * 128, n0 = blockIdx.x * 128;
  int lr = t >> 3, lc = (t & 7) * 8;
  f32x4 acc[4][4] = {};
  for (int k0 = 0; k0 < K; k0 += 64) {
    __syncthreads();
    for (int p = 0; p < 4; ++p) {
      int row = p * 32 + lr;
      *reinterpret_cast<us8*>(&As[row][lc]) =
          *reinterpret_cast<const us8*>(&A[(size_t)(m0 + row) * K + k0 + lc]);
      *reinterpret_cast<us8*>(&Bs[row][lc]) =
          *reinterpret_cast<const us8*>(&Bt[(size_t)(n0 + row) * K + k0 + lc]);
    }
    __syncthreads();
    for (int kk = 0; kk < 64; kk += 32) {
      bf16x8 a[4], b[4];
      for (int mi = 0; mi < 4; ++mi)
        a[mi] = *reinterpret_cast<const bf16x8*>(&As[wm + mi * 16 + fr][kk + fq * 8]);
      for (int ni = 0; ni < 4; ++ni)
        b[ni] = *reinterpret_cast<const bf16x8*>(&Bs[wn + ni * 16 + fr][kk + fq * 8]);
      for (int mi = 0; mi < 4; ++mi)
        for (int ni = 0; ni < 4; ++ni)
          acc[mi][ni] = __builtin_amdgcn_mfma_f32_16x16x32_bf16(a[mi], b[ni], acc[mi][ni], 0, 0, 0);
    }
  }
  for (int mi = 0; mi < 4; ++mi) for (int ni = 0; ni < 4; ++ni) {
    int n  = n0 + wn + ni * 16 + fr;
    int mb = m0 + wm + mi * 16 + fq * 4;
    if (EPI == 0) {
      for (int r = 0; r < 4; ++r)
        Cf[(size_t)(mb + r) * N + n] = acc[mi][ni][r];
    } else {
      int s = n >> 10, c = n & 1023, h = c >> 6, d = c & 63;
      for (int r = 0; r < 4; ++r) {
        int mm = mb + r; int b = mm >> 11, tt = mm & 2047;
        float v = acc[mi][ni][r];
        size_t qk = ((size_t)((b << 4) + h) * 2048 + tt) * 64 + d;
        if (s == 0)      Qb[qk] = f2bf(v * 0.125f);          // fold 1/sqrt(64)
        else if (s == 1) Kb[qk] = f2bf(v);
        else Vt[((size_t)((b << 4) + h) * 64 + d) * 2048 + tt] = f2bf(v);
      }
    }
  }
}

// ---------- flash attention: Q,K [BH][T][64] (Q pre-scaled), Vt [BH][64][T] ----------
// grid (T/64, BH); 4 waves x 16 q-rows; KV tiles of 64; causal.
__global__ __launch_bounds__(256) void k_attn(
    const us* __restrict__ Q, const us* __restrict__ Kv, const us* __restrict__ Vt,
    us* __restrict__ O)
{
  __shared__ us K_lds[64][72];
  __shared__ us V_lds[64][72];
  __shared__ us P_lds[4][16][72];
  int t = threadIdx.x;
  int lane = t & 63, w = t >> 6;
  int fr = lane & 15, fq = lane >> 4;
  int bh = blockIdx.y, qblk = blockIdx.x;
  int q0 = qblk * 64 + w * 16;
  const size_t hb = (size_t)bh * 2048 * 64;

  bf16x8 qf[2];
  qf[0] = *reinterpret_cast<const bf16x8*>(&Q[hb + (size_t)(q0 + fr) * 64 + fq * 8]);
  qf[1] = *reinterpret_cast<const bf16x8*>(&Q[hb + (size_t)(q0 + fr) * 64 + 32 + fq * 8]);

  f32x4 o[4] = {};
  float m_run[4] = {-1e30f, -1e30f, -1e30f, -1e30f};
  float s_run[4] = {};
  int sr = t >> 3, sc = (t & 7) * 8;
  int nt = qblk + 1;
  for (int it = 0; it < nt; ++it) {
    int kv0 = it * 64;
    __syncthreads();
    for (int p = 0; p < 2; ++p) {
      int row = p * 32 + sr;
      *reinterpret_cast<us8*>(&K_lds[row][sc]) =
          *reinterpret_cast<const us8*>(&Kv[hb + (size_t)(kv0 + row) * 64 + sc]);
      *reinterpret_cast<us8*>(&V_lds[row][sc]) =
          *reinterpret_cast<const us8*>(&Vt[hb + (size_t)row * 2048 + kv0 + sc]);
    }
    __syncthreads();

    f32x4 s[4] = {};
    for (int c = 0; c < 2; ++c)
      for (int ni = 0; ni < 4; ++ni) {
        bf16x8 kf = *reinterpret_cast<const bf16x8*>(&K_lds[ni * 16 + fr][c * 32 + fq * 8]);
        s[ni] = __builtin_amdgcn_mfma_f32_16x16x32_bf16(qf[c], kf, s[ni], 0, 0, 0);
      }

    if (kv0 + 64 > q0) {                         // tile touches this wave's diagonal
      for (int ni = 0; ni < 4; ++ni)
        for (int r = 0; r < 4; ++r)
          if (kv0 + ni * 16 + fr > q0 + fq * 4 + r) s[ni][r] = -1e30f;
    }

    float pmax[4];
    for (int r = 0; r < 4; ++r)
      pmax[r] = fmaxf(fmaxf(s[0][r], s[1][r]), fmaxf(s[2][r], s[3][r]));
    for (int msk = 1; msk < 16; msk <<= 1)
      for (int r = 0; r < 4; ++r)
        pmax[r] = fmaxf(pmax[r], __shfl_xor(pmax[r], msk, 64));

    float scl[4];
    for (int r = 0; r < 4; ++r) {
      float mn = fmaxf(m_run[r], pmax[r]);
      scl[r] = __expf(m_run[r] - mn);
      m_run[r] = mn;
    }
    float pv[4][4], psum[4] = {};
    for (int ni = 0; ni < 4; ++ni)
      for (int r = 0; r < 4; ++r) {
        pv[ni][r] = __expf(s[ni][r] - m_run[r]);
        psum[r] += pv[ni][r];
      }
    for (int msk = 1; msk < 16; msk <<= 1)
      for (int r = 0; r < 4; ++r)
        psum[r] += __shfl_xor(psum[r], msk, 64);
    for (int r = 0; r < 4; ++r) s_run[r] = s_run[r] * scl[r] + psum[r];
    for (int df = 0; df < 4; ++df)
      for (int r = 0; r < 4; ++r) o[df][r] *= scl[r];

    for (int ni = 0; ni < 4; ++ni)
      for (int r = 0; r < 4; ++r)
        P_lds[w][fq * 4 + r][ni * 16 + fr] = f2bf(pv[ni][r]);
    asm volatile("s_waitcnt lgkmcnt(0)" ::: "memory");  // wave-local P write->read fence

    for (int c = 0; c < 2; ++c) {
      bf16x8 pa = *reinterpret_cast<const bf16x8*>(&P_lds[w][fr][c * 32 + fq * 8]);
      for (int df = 0; df < 4; ++df) {
        bf16x8 vf = *reinterpret_cast<const bf16x8*>(&V_lds[df * 16 + fr][c * 32 + fq * 8]);
        o[df] = __builtin_amdgcn_mfma_f32_16x16x32_bf16(pa, vf, o[df], 0, 0, 0);
      }
    }
  }

  int b = bh >> 4, h = bh & 15;
  for (int df = 0; df < 4; ++df)
    for (int r = 0; r < 4; ++r) {
      int tt = q0 + fq * 4 + r;
      float val = o[df][r] / s_run[r];
      O[(size_t)(b * 2048 + tt) * 1024 + h * 64 + df * 16 + fr] = f2bf(val);
    }
}

extern "C" void kernel_launch(void* const* d_in, const int* in_sizes, int n_in,
                              void* d_out, int out_size, void* d_ws, size_t ws_size,
                              hipStream_t stream) {
  (void)in_sizes; (void)n_in; (void)out_size; (void)ws_size;
  const float* x      = (const float*)d_in[0];
  const float* w_qkv  = (const float*)d_in[1];
  const float* w_proj = (const float*)d_in[2];
  float* out = (float*)d_out;

  us* xb     = (us*)d_ws;            // 8192*1024
  us* wqkvT  = xb     + 8388608;     // 3072*1024
  us* wprojT = wqkvT  + 3145728;     // 1024*1024
  us* Qb     = wprojT + 1048576;     // [64][2048][64]
  us* Kb     = Qb     + 8388608;
  us* Vtb    = Kb     + 8388608;     // [64][64][2048]
  us* attn   = Vtb    + 8388608;     // [8192][1024]

  k_cvt<<<8192, 256, 0, stream>>>(x, xb, 8388608);
  k_tc<<<dim3(96, 32), dim3(32, 8), 0, stream>>>(w_qkv, wqkvT, 1024, 3072);
  k_tc<<<dim3(32, 32), dim3(32, 8), 0, stream>>>(w_proj, wprojT, 1024, 1024);
  k_gemm<1><<<dim3(24, 64), 256, 0, stream>>>(xb, wqkvT, nullptr, Qb, Kb, Vtb, 8192, 3072, 1024);
  k_attn<<<dim3(32, 64), 256, 0, stream>>>(Qb, Kb, Vtb, attn);
  k_gemm<0><<<dim3(8, 64), 256, 0, stream>>>(attn, wprojT, out, nullptr, nullptr, nullptr, 8192, 1024, 1024);
}

// Round 8
// 360.388 us; speedup vs baseline: 1.2021x; 1.2021x over previous
//
#include <hip/hip_runtime.h>
#include <hip/hip_bf16.h>

// CausalSelfAttention: B=4 T=2048 C=1024 H=16 D=64
// R6: k_attn -> uniform 2-strip causal schedule (33 iters/block, 1024 blocks, all resident)
//     k_gemm -> m97-style global_load_lds(16) staging, linear [128][64] LDS

typedef unsigned short us;
typedef short bf16x8 __attribute__((ext_vector_type(8)));
typedef float f32x4 __attribute__((ext_vector_type(4)));
typedef unsigned short us8 __attribute__((ext_vector_type(8)));

__device__ __forceinline__ us f2bf(float f) {
  union { float f; unsigned u; } v; v.f = f;
  unsigned r = v.u + 0x7fff + ((v.u >> 16) & 1);   // round-to-nearest-even
  return (us)(r >> 16);
}

__device__ __forceinline__ void gload_lds16(const us* g, us* l) {
  __builtin_amdgcn_global_load_lds(
      (const __attribute__((address_space(1))) void*)g,
      (__attribute__((address_space(3))) void*)l, 16, 0, 0);
}

// ---------- fp32 -> bf16, vectorized ----------
__global__ __launch_bounds__(256) void k_cvt(const float* __restrict__ in,
                                             us* __restrict__ out, int n) {
  int i = (blockIdx.x * blockDim.x + threadIdx.x) * 4;
  if (i >= n) return;
  float4 v = *reinterpret_cast<const float4*>(in + i);
  ushort4 o;
  o.x = f2bf(v.x); o.y = f2bf(v.y); o.z = f2bf(v.z); o.w = f2bf(v.w);
  *reinterpret_cast<ushort4*>(out + i) = o;
}

// ---------- transpose-convert: in [R][C] fp32 -> out [C][R] bf16 ----------
__global__ __launch_bounds__(256) void k_tc(const float* __restrict__ in,
                                            us* __restrict__ out, int R, int C) {
  __shared__ float tile[32][33];
  int c0 = blockIdx.x * 32, r0 = blockIdx.y * 32;
  int tx = threadIdx.x, ty = threadIdx.y;          // block (32,8)
  for (int j = 0; j < 32; j += 8)
    tile[ty + j][tx] = in[(size_t)(r0 + ty + j) * C + c0 + tx];
  __syncthreads();
  for (int j = 0; j < 32; j += 8)
    out[(size_t)(c0 + ty + j) * R + r0 + tx] = f2bf(tile[tx][ty + j]);
}

// ---------- bf16 GEMM: A[M][K] * Bt[N][K]^T.  EPI=0: fp32 C.  EPI=1: QKV scatter ----------
// 128x128 tile, BK=64, 4 waves (2x2), 4x4 frags of 16x16x32. global_load_lds staging.
template<int EPI>
__global__ __launch_bounds__(256) void k_gemm(
    const us* __restrict__ A, const us* __restrict__ Bt,
    float* __restrict__ Cf,
    us* __restrict__ Qb, us* __restrict__ Kb, us* __restrict__ Vt,
    int M, int N, int K)
{
  __shared__ us As[128][64];   // linear: global_load_lds dest must be contiguous (m97)
  __shared__ us Bs[128][64];
  int t = threadIdx.x;
  int lane = t & 63, w = t >> 6;
  int wm = (w >> 1) * 64, wn = (w & 1) * 64;
  int fr = lane & 15, fq = lane >> 4;
  int m0 = blockIdx.y * 128, n0 = blockIdx.x * 128;
  int srow = lane >> 3, scol = (lane & 7) * 8;   // per-call: 8 rows x 128B
  f32x4 acc[4][4] = {};
  for (int k0 = 0; k0 < K; k0 += 64) {
    __syncthreads();
    for (int p = 0; p < 4; ++p) {
      int row = w * 32 + p * 8;                  // wave-uniform LDS base row
      gload_lds16(&A[(size_t)(m0 + row + srow) * K + k0 + scol], &As[row][0]);
      gload_lds16(&Bt[(size_t)(n0 + row + srow) * K + k0 + scol], &Bs[row][0]);
    }
    __syncthreads();                             // compiler drains vmcnt before barrier
    for (int kk = 0; kk < 64; kk += 32) {
      bf16x8 a[4], b[4];
      for (int mi = 0; mi < 4; ++mi)
        a[mi] = *reinterpret_cast<const bf16x8*>(&As[wm + mi * 16 + fr][kk + fq * 8]);
      for (int ni = 0; ni < 4; ++ni)
        b[ni] = *reinterpret_cast<const bf16x8*>(&Bs[wn + ni * 16 + fr][kk + fq * 8]);
      for (int mi = 0; mi < 4; ++mi)
        for (int ni = 0; ni < 4; ++ni)
          acc[mi][ni] = __builtin_amdgcn_mfma_f32_16x16x32_bf16(a[mi], b[ni], acc[mi][ni], 0, 0, 0);
    }
  }
  for (int mi = 0; mi < 4; ++mi) for (int ni = 0; ni < 4; ++ni) {
    int n  = n0 + wn + ni * 16 + fr;
    int mb = m0 + wm + mi * 16 + fq * 4;
    if (EPI == 0) {
      for (int r = 0; r < 4; ++r)
        Cf[(size_t)(mb + r) * N + n] = acc[mi][ni][r];
    } else {
      int s = n >> 10, c = n & 1023, h = c >> 6, d = c & 63;
      for (int r = 0; r < 4; ++r) {
        int mm = mb + r; int b = mm >> 11, tt = mm & 2047;
        float v = acc[mi][ni][r];
        size_t qk = ((size_t)((b << 4) + h) * 2048 + tt) * 64 + d;
        if (s == 0)      Qb[qk] = f2bf(v * 0.125f);          // fold 1/sqrt(64)
        else if (s == 1) Kb[qk] = f2bf(v);
        else Vt[((size_t)((b << 4) + h) * 64 + d) * 2048 + tt] = f2bf(v);
      }
    }
  }
}

// ---------- flash attention: Q,K [BH][T][64] (Q pre-scaled), Vt [BH][64][T] ----------
// grid (16, BH); block px handles q-strips px and 31-px -> uniform 33 KV-tiles/block.
__global__ __launch_bounds__(256) void k_attn(
    const us* __restrict__ Q, const us* __restrict__ Kv, const us* __restrict__ Vt,
    us* __restrict__ O)
{
  __shared__ us K_lds[64][72];
  __shared__ us V_lds[64][72];
  __shared__ us P_lds[4][16][72];
  int t = threadIdx.x;
  int lane = t & 63, w = t >> 6;
  int fr = lane & 15, fq = lane >> 4;
  int bh = blockIdx.y, px = blockIdx.x;
  const size_t hb = (size_t)bh * 2048 * 64;
  int sr = t >> 3, sc = (t & 7) * 8;
  int b = bh >> 4, h = bh & 15;

  for (int sidx = 0; sidx < 2; ++sidx) {
    int qblk = sidx ? (31 - px) : px;
    int q0 = qblk * 64 + w * 16;

    bf16x8 qf[2];
    qf[0] = *reinterpret_cast<const bf16x8*>(&Q[hb + (size_t)(q0 + fr) * 64 + fq * 8]);
    qf[1] = *reinterpret_cast<const bf16x8*>(&Q[hb + (size_t)(q0 + fr) * 64 + 32 + fq * 8]);

    f32x4 o[4] = {};
    float m_run[4] = {-1e30f, -1e30f, -1e30f, -1e30f};
    float s_run[4] = {};
    int nt = qblk + 1;
    for (int it = 0; it < nt; ++it) {
      int kv0 = it * 64;
      __syncthreads();
      for (int p = 0; p < 2; ++p) {
        int row = p * 32 + sr;
        *reinterpret_cast<us8*>(&K_lds[row][sc]) =
            *reinterpret_cast<const us8*>(&Kv[hb + (size_t)(kv0 + row) * 64 + sc]);
        *reinterpret_cast<us8*>(&V_lds[row][sc]) =
            *reinterpret_cast<const us8*>(&Vt[hb + (size_t)row * 2048 + kv0 + sc]);
      }
      __syncthreads();

      f32x4 s[4] = {};
      for (int c = 0; c < 2; ++c)
        for (int ni = 0; ni < 4; ++ni) {
          bf16x8 kf = *reinterpret_cast<const bf16x8*>(&K_lds[ni * 16 + fr][c * 32 + fq * 8]);
          s[ni] = __builtin_amdgcn_mfma_f32_16x16x32_bf16(qf[c], kf, s[ni], 0, 0, 0);
        }

      if (kv0 + 64 > q0) {                       // tile touches this wave's diagonal
        for (int ni = 0; ni < 4; ++ni)
          for (int r = 0; r < 4; ++r)
            if (kv0 + ni * 16 + fr > q0 + fq * 4 + r) s[ni][r] = -1e30f;
      }

      float pmax[4];
      for (int r = 0; r < 4; ++r)
        pmax[r] = fmaxf(fmaxf(s[0][r], s[1][r]), fmaxf(s[2][r], s[3][r]));
      for (int msk = 1; msk < 16; msk <<= 1)
        for (int r = 0; r < 4; ++r)
          pmax[r] = fmaxf(pmax[r], __shfl_xor(pmax[r], msk, 64));

      float scl[4];
      for (int r = 0; r < 4; ++r) {
        float mn = fmaxf(m_run[r], pmax[r]);
        scl[r] = __expf(m_run[r] - mn);
        m_run[r] = mn;
      }
      float pv[4][4], psum[4] = {};
      for (int ni = 0; ni < 4; ++ni)
        for (int r = 0; r < 4; ++r) {
          pv[ni][r] = __expf(s[ni][r] - m_run[r]);
          psum[r] += pv[ni][r];
        }
      for (int msk = 1; msk < 16; msk <<= 1)
        for (int r = 0; r < 4; ++r)
          psum[r] += __shfl_xor(psum[r], msk, 64);
      for (int r = 0; r < 4; ++r) s_run[r] = s_run[r] * scl[r] + psum[r];
      for (int df = 0; df < 4; ++df)
        for (int r = 0; r < 4; ++r) o[df][r] *= scl[r];

      for (int ni = 0; ni < 4; ++ni)
        for (int r = 0; r < 4; ++r)
          P_lds[w][fq * 4 + r][ni * 16 + fr] = f2bf(pv[ni][r]);
      asm volatile("s_waitcnt lgkmcnt(0)" ::: "memory");  // wave-local P write->read fence

      for (int c = 0; c < 2; ++c) {
        bf16x8 pa = *reinterpret_cast<const bf16x8*>(&P_lds[w][fr][c * 32 + fq * 8]);
        for (int df = 0; df < 4; ++df) {
          bf16x8 vf = *reinterpret_cast<const bf16x8*>(&V_lds[df * 16 + fr][c * 32 + fq * 8]);
          o[df] = __builtin_amdgcn_mfma_f32_16x16x32_bf16(pa, vf, o[df], 0, 0, 0);
        }
      }
    }

    for (int df = 0; df < 4; ++df)
      for (int r = 0; r < 4; ++r) {
        int tt = q0 + fq * 4 + r;
        float val = o[df][r] / s_run[r];
        O[(size_t)(b * 2048 + tt) * 1024 + h * 64 + df * 16 + fr] = f2bf(val);
      }
  }
}

extern "C" void kernel_launch(void* const* d_in, const int* in_sizes, int n_in,
                              void* d_out, int out_size, void* d_ws, size_t ws_size,
                              hipStream_t stream) {
  (void)in_sizes; (void)n_in; (void)out_size; (void)ws_size;
  const float* x      = (const float*)d_in[0];
  const float* w_qkv  = (const float*)d_in[1];
  const float* w_proj = (const float*)d_in[2];
  float* out = (float*)d_out;

  us* xb     = (us*)d_ws;            // 8192*1024
  us* wqkvT  = xb     + 8388608;     // 3072*1024
  us* wprojT = wqkvT  + 3145728;     // 1024*1024
  us* Qb     = wprojT + 1048576;     // [64][2048][64]
  us* Kb     = Qb     + 8388608;
  us* Vtb    = Kb     + 8388608;     // [64][64][2048]
  us* attn   = Vtb    + 8388608;     // [8192][1024]

  k_cvt<<<8192, 256, 0, stream>>>(x, xb, 8388608);
  k_tc<<<dim3(96, 32), dim3(32, 8), 0, stream>>>(w_qkv, wqkvT, 1024, 3072);
  k_tc<<<dim3(32, 32), dim3(32, 8), 0, stream>>>(w_proj, wprojT, 1024, 1024);
  k_gemm<1><<<dim3(24, 64), 256, 0, stream>>>(xb, wqkvT, nullptr, Qb, Kb, Vtb, 8192, 3072, 1024);
  k_attn<<<dim3(16, 64), 256, 0, stream>>>(Qb, Kb, Vtb, attn);
  k_gemm<0><<<dim3(8, 64), 256, 0, stream>>>(attn, wprojT, out, nullptr, nullptr, nullptr, 8192, 1024, 1024);
}

// Round 14
// 344.371 us; speedup vs baseline: 1.2580x; 1.0465x over previous
//
#include <hip/hip_runtime.h>
#include <hip/hip_bf16.h>

// CausalSelfAttention: B=4 T=2048 C=1024 H=16 D=64
// R8: k_attn -> 128-row q-blocks, 8 waves/block (512 thr), strip-paired (px,15-px),
//     exp2-domain softmax (log2e folded into Q scale), packed bf16 converts.
// k_gemm: m97-style global_load_lds(16) staging (unchanged from R6).

typedef unsigned short us;
typedef short bf16x8 __attribute__((ext_vector_type(8)));
typedef float f32x4 __attribute__((ext_vector_type(4)));
typedef unsigned short us8 __attribute__((ext_vector_type(8)));

extern "C" __device__ float __ocml_native_exp2_f32(float);  // v_exp_f32

__device__ __forceinline__ us f2bf(float f) {
  union { float f; unsigned u; } v; v.f = f;
  unsigned r = v.u + 0x7fff + ((v.u >> 16) & 1);   // round-to-nearest-even
  return (us)(r >> 16);
}
__device__ __forceinline__ us f2bf_hw(float f) {   // compiler may pack v_cvt_pk_bf16_f32
  __hip_bfloat16 h = __float2bfloat16(f);
  return *reinterpret_cast<us*>(&h);
}

__device__ __forceinline__ void gload_lds16(const us* g, us* l) {
  __builtin_amdgcn_global_load_lds(
      (const __attribute__((address_space(1))) void*)g,
      (__attribute__((address_space(3))) void*)l, 16, 0, 0);
}

// ---------- fp32 -> bf16, vectorized ----------
__global__ __launch_bounds__(256) void k_cvt(const float* __restrict__ in,
                                             us* __restrict__ out, int n) {
  int i = (blockIdx.x * blockDim.x + threadIdx.x) * 4;
  if (i >= n) return;
  float4 v = *reinterpret_cast<const float4*>(in + i);
  ushort4 o;
  o.x = f2bf(v.x); o.y = f2bf(v.y); o.z = f2bf(v.z); o.w = f2bf(v.w);
  *reinterpret_cast<ushort4*>(out + i) = o;
}

// ---------- transpose-convert: in [R][C] fp32 -> out [C][R] bf16 ----------
__global__ __launch_bounds__(256) void k_tc(const float* __restrict__ in,
                                            us* __restrict__ out, int R, int C) {
  __shared__ float tile[32][33];
  int c0 = blockIdx.x * 32, r0 = blockIdx.y * 32;
  int tx = threadIdx.x, ty = threadIdx.y;          // block (32,8)
  for (int j = 0; j < 32; j += 8)
    tile[ty + j][tx] = in[(size_t)(r0 + ty + j) * C + c0 + tx];
  __syncthreads();
  for (int j = 0; j < 32; j += 8)
    out[(size_t)(c0 + ty + j) * R + r0 + tx] = f2bf(tile[tx][ty + j]);
}

// ---------- bf16 GEMM: A[M][K] * Bt[N][K]^T.  EPI=0: fp32 C.  EPI=1: QKV scatter ----------
template<int EPI>
__global__ __launch_bounds__(256) void k_gemm(
    const us* __restrict__ A, const us* __restrict__ Bt,
    float* __restrict__ Cf,
    us* __restrict__ Qb, us* __restrict__ Kb, us* __restrict__ Vt,
    int M, int N, int K)
{
  __shared__ us As[128][64];   // linear: global_load_lds dest must be contiguous (m97)
  __shared__ us Bs[128][64];
  int t = threadIdx.x;
  int lane = t & 63, w = t >> 6;
  int wm = (w >> 1) * 64, wn = (w & 1) * 64;
  int fr = lane & 15, fq = lane >> 4;
  int m0 = blockIdx.y * 128, n0 = blockIdx.x * 128;
  int srow = lane >> 3, scol = (lane & 7) * 8;   // per-call: 8 rows x 128B
  f32x4 acc[4][4] = {};
  for (int k0 = 0; k0 < K; k0 += 64) {
    __syncthreads();
    for (int p = 0; p < 4; ++p) {
      int row = w * 32 + p * 8;                  // wave-uniform LDS base row
      gload_lds16(&A[(size_t)(m0 + row + srow) * K + k0 + scol], &As[row][0]);
      gload_lds16(&Bt[(size_t)(n0 + row + srow) * K + k0 + scol], &Bs[row][0]);
    }
    __syncthreads();                             // drains vmcnt before barrier
    for (int kk = 0; kk < 64; kk += 32) {
      bf16x8 a[4], b[4];
      for (int mi = 0; mi < 4; ++mi)
        a[mi] = *reinterpret_cast<const bf16x8*>(&As[wm + mi * 16 + fr][kk + fq * 8]);
      for (int ni = 0; ni < 4; ++ni)
        b[ni] = *reinterpret_cast<const bf16x8*>(&Bs[wn + ni * 16 + fr][kk + fq * 8]);
      for (int mi = 0; mi < 4; ++mi)
        for (int ni = 0; ni < 4; ++ni)
          acc[mi][ni] = __builtin_amdgcn_mfma_f32_16x16x32_bf16(a[mi], b[ni], acc[mi][ni], 0, 0, 0);
    }
  }
  for (int mi = 0; mi < 4; ++mi) for (int ni = 0; ni < 4; ++ni) {
    int n  = n0 + wn + ni * 16 + fr;
    int mb = m0 + wm + mi * 16 + fq * 4;
    if (EPI == 0) {
      for (int r = 0; r < 4; ++r)
        Cf[(size_t)(mb + r) * N + n] = acc[mi][ni][r];
    } else {
      int s = n >> 10, c = n & 1023, h = c >> 6, d = c & 63;
      for (int r = 0; r < 4; ++r) {
        int mm = mb + r; int b = mm >> 11, tt = mm & 2047;
        float v = acc[mi][ni][r];
        size_t qk = ((size_t)((b << 4) + h) * 2048 + tt) * 64 + d;
        if (s == 0)      Qb[qk] = f2bf(v * 0.1803368801111244f); // 1/8 * log2(e)
        else if (s == 1) Kb[qk] = f2bf(v);
        else Vt[((size_t)((b << 4) + h) * 64 + d) * 2048 + tt] = f2bf(v);
      }
    }
  }
}

// ---------- flash attention: Q,K [BH][T][64] (Q pre-scaled by log2e/8), Vt [BH][64][T] ----------
// grid (8, BH), 512 thr = 8 waves x 16 q-rows = 128-row q-block.
// Block px handles q-blocks px and 15-px -> uniform 34 KV-tile iters.
__global__ __launch_bounds__(512) void k_attn(
    const us* __restrict__ Q, const us* __restrict__ Kv, const us* __restrict__ Vt,
    us* __restrict__ O)
{
  __shared__ us K_lds[64][72];
  __shared__ us V_lds[64][72];
  __shared__ us P_lds[8][16][72];
  int t = threadIdx.x;
  int lane = t & 63, w = t >> 6;          // w in [0,8)
  int fr = lane & 15, fq = lane >> 4;
  int bh = blockIdx.y, px = blockIdx.x;   // px in [0,8)
  const size_t hb = (size_t)bh * 2048 * 64;
  int sr = t >> 3, sc = (t & 7) * 8;      // 512 thr: 64 rows x 128B
  int b = bh >> 4, h = bh & 15;

  for (int sidx = 0; sidx < 2; ++sidx) {
    int qblk = sidx ? (15 - px) : px;
    int q0 = qblk * 128 + w * 16;         // this wave's 16 q-rows

    bf16x8 qf[2];
    qf[0] = *reinterpret_cast<const bf16x8*>(&Q[hb + (size_t)(q0 + fr) * 64 + fq * 8]);
    qf[1] = *reinterpret_cast<const bf16x8*>(&Q[hb + (size_t)(q0 + fr) * 64 + 32 + fq * 8]);

    f32x4 o[4] = {};
    float m_run[4] = {-1e30f, -1e30f, -1e30f, -1e30f};
    float s_run[4] = {};
    int nt = 2 * qblk + 2;
    for (int it = 0; it < nt; ++it) {
      int kv0 = it * 64;
      __syncthreads();
      *reinterpret_cast<us8*>(&K_lds[sr][sc]) =
          *reinterpret_cast<const us8*>(&Kv[hb + (size_t)(kv0 + sr) * 64 + sc]);
      *reinterpret_cast<us8*>(&V_lds[sr][sc]) =
          *reinterpret_cast<const us8*>(&Vt[hb + (size_t)sr * 2048 + kv0 + sc]);
      __syncthreads();

      if (kv0 > q0 + 15) continue;        // wave-uniform: tile fully masked for this wave

      f32x4 s[4] = {};
      for (int c = 0; c < 2; ++c)
        for (int ni = 0; ni < 4; ++ni) {
          bf16x8 kf = *reinterpret_cast<const bf16x8*>(&K_lds[ni * 16 + fr][c * 32 + fq * 8]);
          s[ni] = __builtin_amdgcn_mfma_f32_16x16x32_bf16(qf[c], kf, s[ni], 0, 0, 0);
        }

      if (kv0 + 64 > q0) {                // tile touches this wave's diagonal
        for (int ni = 0; ni < 4; ++ni)
          for (int r = 0; r < 4; ++r)
            if (kv0 + ni * 16 + fr > q0 + fq * 4 + r) s[ni][r] = -1e30f;
      }

      float pmax[4];
      for (int r = 0; r < 4; ++r)
        pmax[r] = fmaxf(fmaxf(s[0][r], s[1][r]), fmaxf(s[2][r], s[3][r]));
      for (int msk = 1; msk < 16; msk <<= 1)
        for (int r = 0; r < 4; ++r)
          pmax[r] = fmaxf(pmax[r], __shfl_xor(pmax[r], msk, 64));

      float scl[4];
      for (int r = 0; r < 4; ++r) {
        float mn = fmaxf(m_run[r], pmax[r]);
        scl[r] = __ocml_native_exp2_f32(m_run[r] - mn);   // exp2 domain
        m_run[r] = mn;
      }
      float pv[4][4], psum[4] = {};
      for (int ni = 0; ni < 4; ++ni)
        for (int r = 0; r < 4; ++r) {
          pv[ni][r] = __ocml_native_exp2_f32(s[ni][r] - m_run[r]);
          psum[r] += pv[ni][r];
        }
      for (int msk = 1; msk < 16; msk <<= 1)
        for (int r = 0; r < 4; ++r)
          psum[r] += __shfl_xor(psum[r], msk, 64);
      for (int r = 0; r < 4; ++r) s_run[r] = s_run[r] * scl[r] + psum[r];
      for (int df = 0; df < 4; ++df)
        for (int r = 0; r < 4; ++r) o[df][r] *= scl[r];

      for (int ni = 0; ni < 4; ++ni)
        for (int r = 0; r < 4; ++r)
          P_lds[w][fq * 4 + r][ni * 16 + fr] = f2bf_hw(pv[ni][r]);
      asm volatile("s_waitcnt lgkmcnt(0)" ::: "memory");  // wave-local P write->read fence

      for (int c = 0; c < 2; ++c) {
        bf16x8 pa = *reinterpret_cast<const bf16x8*>(&P_lds[w][fr][c * 32 + fq * 8]);
        for (int df = 0; df < 4; ++df) {
          bf16x8 vf = *reinterpret_cast<const bf16x8*>(&V_lds[df * 16 + fr][c * 32 + fq * 8]);
          o[df] = __builtin_amdgcn_mfma_f32_16x16x32_bf16(pa, vf, o[df], 0, 0, 0);
        }
      }
    }

    for (int df = 0; df < 4; ++df)
      for (int r = 0; r < 4; ++r) {
        int tt = q0 + fq * 4 + r;
        float val = o[df][r] / s_run[r];
        O[(size_t)(b * 2048 + tt) * 1024 + h * 64 + df * 16 + fr] = f2bf_hw(val);
      }
  }
}

extern "C" void kernel_launch(void* const* d_in, const int* in_sizes, int n_in,
                              void* d_out, int out_size, void* d_ws, size_t ws_size,
                              hipStream_t stream) {
  (void)in_sizes; (void)n_in; (void)out_size; (void)ws_size;
  const float* x      = (const float*)d_in[0];
  const float* w_qkv  = (const float*)d_in[1];
  const float* w_proj = (const float*)d_in[2];
  float* out = (float*)d_out;

  us* xb     = (us*)d_ws;            // 8192*1024
  us* wqkvT  = xb     + 8388608;     // 3072*1024
  us* wprojT = wqkvT  + 3145728;     // 1024*1024
  us* Qb     = wprojT + 1048576;     // [64][2048][64]
  us* Kb     = Qb     + 8388608;
  us* Vtb    = Kb     + 8388608;     // [64][64][2048]
  us* attn   = Vtb    + 8388608;     // [8192][1024]

  k_cvt<<<8192, 256, 0, stream>>>(x, xb, 8388608);
  k_tc<<<dim3(96, 32), dim3(32, 8), 0, stream>>>(w_qkv, wqkvT, 1024, 3072);
  k_tc<<<dim3(32, 32), dim3(32, 8), 0, stream>>>(w_proj, wprojT, 1024, 1024);
  k_gemm<1><<<dim3(24, 64), 256, 0, stream>>>(xb, wqkvT, nullptr, Qb, Kb, Vtb, 8192, 3072, 1024);
  k_attn<<<dim3(8, 64), 512, 0, stream>>>(Qb, Kb, Vtb, attn);
  k_gemm<0><<<dim3(8, 64), 256, 0, stream>>>(attn, wprojT, out, nullptr, nullptr, nullptr, 8192, 1024, 1024);
}

// Round 16
// 323.455 us; speedup vs baseline: 1.3394x; 1.0647x over previous
//
#include <hip/hip_runtime.h>
#include <hip/hip_bf16.h>

// CausalSelfAttention: B=4 T=2048 C=1024 H=16 D=64
// R14: k_attn += (1) XOR-swizzled linear K/V LDS (reg-staged, both-sides swizzle),
//      (2) T14 async-stage (issue next-tile loads under compute),
//      (3) T13 defer-rescale THR=8, (4) XCD-clustered bh mapping.
// k_gemm / prep unchanged (GEMM 8-phase port queued once its counters surface).

typedef unsigned short us;
typedef short bf16x8 __attribute__((ext_vector_type(8)));
typedef float f32x4 __attribute__((ext_vector_type(4)));
typedef unsigned short us8 __attribute__((ext_vector_type(8)));

extern "C" __device__ float __ocml_native_exp2_f32(float);  // v_exp_f32

__device__ __forceinline__ us f2bf(float f) {
  union { float f; unsigned u; } v; v.f = f;
  unsigned r = v.u + 0x7fff + ((v.u >> 16) & 1);   // round-to-nearest-even
  return (us)(r >> 16);
}
__device__ __forceinline__ us f2bf_hw(float f) {
  __hip_bfloat16 h = __float2bfloat16(f);
  return *reinterpret_cast<us*>(&h);
}

__device__ __forceinline__ void gload_lds16(const us* g, us* l) {
  __builtin_amdgcn_global_load_lds(
      (const __attribute__((address_space(1))) void*)g,
      (__attribute__((address_space(3))) void*)l, 16, 0, 0);
}

// ---------- fp32 -> bf16, vectorized ----------
__global__ __launch_bounds__(256) void k_cvt(const float* __restrict__ in,
                                             us* __restrict__ out, int n) {
  int i = (blockIdx.x * blockDim.x + threadIdx.x) * 4;
  if (i >= n) return;
  float4 v = *reinterpret_cast<const float4*>(in + i);
  ushort4 o;
  o.x = f2bf(v.x); o.y = f2bf(v.y); o.z = f2bf(v.z); o.w = f2bf(v.w);
  *reinterpret_cast<ushort4*>(out + i) = o;
}

// ---------- transpose-convert: in [R][C] fp32 -> out [C][R] bf16 ----------
__global__ __launch_bounds__(256) void k_tc(const float* __restrict__ in,
                                            us* __restrict__ out, int R, int C) {
  __shared__ float tile[32][33];
  int c0 = blockIdx.x * 32, r0 = blockIdx.y * 32;
  int tx = threadIdx.x, ty = threadIdx.y;          // block (32,8)
  for (int j = 0; j < 32; j += 8)
    tile[ty + j][tx] = in[(size_t)(r0 + ty + j) * C + c0 + tx];
  __syncthreads();
  for (int j = 0; j < 32; j += 8)
    out[(size_t)(c0 + ty + j) * R + r0 + tx] = f2bf(tile[tx][ty + j]);
}

// ---------- bf16 GEMM: A[M][K] * Bt[N][K]^T.  EPI=0: fp32 C.  EPI=1: QKV scatter ----------
template<int EPI>
__global__ __launch_bounds__(256) void k_gemm(
    const us* __restrict__ A, const us* __restrict__ Bt,
    float* __restrict__ Cf,
    us* __restrict__ Qb, us* __restrict__ Kb, us* __restrict__ Vt,
    int M, int N, int K)
{
  __shared__ us As[128][64];   // linear: global_load_lds dest must be contiguous (m97)
  __shared__ us Bs[128][64];
  int t = threadIdx.x;
  int lane = t & 63, w = t >> 6;
  int wm = (w >> 1) * 64, wn = (w & 1) * 64;
  int fr = lane & 15, fq = lane >> 4;
  int m0 = blockIdx.y * 128, n0 = blockIdx.x * 128;
  int srow = lane >> 3, scol = (lane & 7) * 8;   // per-call: 8 rows x 128B
  f32x4 acc[4][4] = {};
  for (int k0 = 0; k0 < K; k0 += 64) {
    __syncthreads();
    for (int p = 0; p < 4; ++p) {
      int row = w * 32 + p * 8;                  // wave-uniform LDS base row
      gload_lds16(&A[(size_t)(m0 + row + srow) * K + k0 + scol], &As[row][0]);
      gload_lds16(&Bt[(size_t)(n0 + row + srow) * K + k0 + scol], &Bs[row][0]);
    }
    __syncthreads();                             // drains vmcnt before barrier
    for (int kk = 0; kk < 64; kk += 32) {
      bf16x8 a[4], b[4];
      for (int mi = 0; mi < 4; ++mi)
        a[mi] = *reinterpret_cast<const bf16x8*>(&As[wm + mi * 16 + fr][kk + fq * 8]);
      for (int ni = 0; ni < 4; ++ni)
        b[ni] = *reinterpret_cast<const bf16x8*>(&Bs[wn + ni * 16 + fr][kk + fq * 8]);
      for (int mi = 0; mi < 4; ++mi)
        for (int ni = 0; ni < 4; ++ni)
          acc[mi][ni] = __builtin_amdgcn_mfma_f32_16x16x32_bf16(a[mi], b[ni], acc[mi][ni], 0, 0, 0);
    }
  }
  for (int mi = 0; mi < 4; ++mi) for (int ni = 0; ni < 4; ++ni) {
    int n  = n0 + wn + ni * 16 + fr;
    int mb = m0 + wm + mi * 16 + fq * 4;
    if (EPI == 0) {
      for (int r = 0; r < 4; ++r)
        Cf[(size_t)(mb + r) * N + n] = acc[mi][ni][r];
    } else {
      int s = n >> 10, c = n & 1023, h = c >> 6, d = c & 63;
      for (int r = 0; r < 4; ++r) {
        int mm = mb + r; int b = mm >> 11, tt = mm & 2047;
        float v = acc[mi][ni][r];
        size_t qk = ((size_t)((b << 4) + h) * 2048 + tt) * 64 + d;
        if (s == 0)      Qb[qk] = f2bf(v * 0.1803368801111244f); // 1/8 * log2(e)
        else if (s == 1) Kb[qk] = f2bf(v);
        else Vt[((size_t)((b << 4) + h) * 64 + d) * 2048 + tt] = f2bf(v);
      }
    }
  }
}

// ---------- flash attention: Q,K [BH][T][64] (Q pre-scaled by log2e/8), Vt [BH][64][T] ----------
// grid (8, BH) = 512 blocks, 512 thr = 8 waves x 16 q-rows = 128-row q-block.
// Block handles q-blocks px and 15-px (uniform 34 KV-tiles). XCD-clustered bh mapping.
// K/V LDS: linear [64][64], slot-swizzled p = s ^ (row&7); reg-staged with async split.
__global__ __launch_bounds__(512) void k_attn(
    const us* __restrict__ Q, const us* __restrict__ Kv, const us* __restrict__ Vt,
    us* __restrict__ O)
{
  __shared__ us K_lds[64][64];
  __shared__ us V_lds[64][64];
  __shared__ us P_lds[8][16][72];
  int t = threadIdx.x;
  int lane = t & 63, w = t >> 6;          // w in [0,8)
  int fr = lane & 15, fq = lane >> 4;
  // XCD clustering: consecutive dispatch ids round-robin XCDs; give each XCD one bh-octet.
  int flat = blockIdx.y * 8 + blockIdx.x;        // 0..511
  int xcd = flat & 7, idx = flat >> 3;
  int bh = (idx & 7) | (xcd << 3);               // blocks of bh stay on one XCD
  int px = idx >> 3;                             // 0..7
  const size_t hb = (size_t)bh * 2048 * 64;
  int sr = t >> 3;                               // 0..63: staging row
  int ss = t & 7;                                // logical 16B slot
  int ssw = (ss ^ (sr & 7)) * 8;                 // swizzled slot (elems)
  int fr7 = fr & 7;
  int b = bh >> 4, h = bh & 15;

  for (int sidx = 0; sidx < 2; ++sidx) {
    int qblk = sidx ? (15 - px) : px;
    int q0 = qblk * 128 + w * 16;         // this wave's 16 q-rows

    bf16x8 qf[2];
    qf[0] = *reinterpret_cast<const bf16x8*>(&Q[hb + (size_t)(q0 + fr) * 64 + fq * 8]);
    qf[1] = *reinterpret_cast<const bf16x8*>(&Q[hb + (size_t)(q0 + fr) * 64 + 32 + fq * 8]);

    f32x4 o[4] = {};
    float m_run[4] = {-1e30f, -1e30f, -1e30f, -1e30f};
    float s_run[4] = {};
    int nt = 2 * qblk + 2;

    // prologue: tile 0 into regs
    us8 kreg = *reinterpret_cast<const us8*>(&Kv[hb + (size_t)sr * 64 + ss * 8]);
    us8 vreg = *reinterpret_cast<const us8*>(&Vt[hb + (size_t)sr * 2048 + ss * 8]);

    for (int it = 0; it < nt; ++it) {
      int kv0 = it * 64;
      __syncthreads();                     // prev iter's LDS reads done
      *reinterpret_cast<us8*>(&K_lds[sr][ssw]) = kreg;
      *reinterpret_cast<us8*>(&V_lds[sr][ssw]) = vreg;
      if (it + 1 < nt) {                   // issue next-tile loads; vmcnt waited at next write
        int kn = kv0 + 64;
        kreg = *reinterpret_cast<const us8*>(&Kv[hb + (size_t)(kn + sr) * 64 + ss * 8]);
        vreg = *reinterpret_cast<const us8*>(&Vt[hb + (size_t)sr * 2048 + kn + ss * 8]);
      }
      __syncthreads();                     // staged tile visible

      if (kv0 > q0 + 15) continue;         // wave-uniform: fully masked for this wave

      f32x4 s[4] = {};
      for (int c = 0; c < 2; ++c)
        for (int ni = 0; ni < 4; ++ni) {
          int sl = (((c << 2) | fq) ^ fr7) * 8;
          bf16x8 kf = *reinterpret_cast<const bf16x8*>(&K_lds[ni * 16 + fr][sl]);
          s[ni] = __builtin_amdgcn_mfma_f32_16x16x32_bf16(qf[c], kf, s[ni], 0, 0, 0);
        }

      if (kv0 + 64 > q0) {                 // tile touches this wave's diagonal
        for (int ni = 0; ni < 4; ++ni)
          for (int r = 0; r < 4; ++r)
            if (kv0 + ni * 16 + fr > q0 + fq * 4 + r) s[ni][r] = -1e30f;
      }

      float pmax[4];
      for (int r = 0; r < 4; ++r)
        pmax[r] = fmaxf(fmaxf(s[0][r], s[1][r]), fmaxf(s[2][r], s[3][r]));
      for (int msk = 1; msk < 16; msk <<= 1)
        for (int r = 0; r < 4; ++r)
          pmax[r] = fmaxf(pmax[r], __shfl_xor(pmax[r], msk, 64));

      // T13 defer-rescale: only rescale when some row grew by > 8 (exp2 domain)
      float worst = fmaxf(fmaxf(pmax[0] - m_run[0], pmax[1] - m_run[1]),
                          fmaxf(pmax[2] - m_run[2], pmax[3] - m_run[3]));
      if (__any(worst > 8.0f)) {
        for (int r = 0; r < 4; ++r) {
          float mn = fmaxf(m_run[r], pmax[r]);
          float scl = __ocml_native_exp2_f32(m_run[r] - mn);
          m_run[r] = mn;
          s_run[r] *= scl;
          for (int df = 0; df < 4; ++df) o[df][r] *= scl;
        }
      }

      float pv[4][4], psum[4] = {};
      for (int ni = 0; ni < 4; ++ni)
        for (int r = 0; r < 4; ++r) {
          pv[ni][r] = __ocml_native_exp2_f32(s[ni][r] - m_run[r]);
          psum[r] += pv[ni][r];
        }
      for (int msk = 1; msk < 16; msk <<= 1)
        for (int r = 0; r < 4; ++r)
          psum[r] += __shfl_xor(psum[r], msk, 64);
      for (int r = 0; r < 4; ++r) s_run[r] += psum[r];

      for (int ni = 0; ni < 4; ++ni)
        for (int r = 0; r < 4; ++r)
          P_lds[w][fq * 4 + r][ni * 16 + fr] = f2bf_hw(pv[ni][r]);
      asm volatile("s_waitcnt lgkmcnt(0)" ::: "memory");  // wave-local P write->read fence

      for (int c = 0; c < 2; ++c) {
        bf16x8 pa = *reinterpret_cast<const bf16x8*>(&P_lds[w][fr][c * 32 + fq * 8]);
        for (int df = 0; df < 4; ++df) {
          int sl = (((c << 2) | fq) ^ fr7) * 8;
          bf16x8 vf = *reinterpret_cast<const bf16x8*>(&V_lds[df * 16 + fr][sl]);
          o[df] = __builtin_amdgcn_mfma_f32_16x16x32_bf16(pa, vf, o[df], 0, 0, 0);
        }
      }
    }

    for (int df = 0; df < 4; ++df)
      for (int r = 0; r < 4; ++r) {
        int tt = q0 + fq * 4 + r;
        float val = o[df][r] / s_run[r];
        O[(size_t)(b * 2048 + tt) * 1024 + h * 64 + df * 16 + fr] = f2bf_hw(val);
      }
  }
}

extern "C" void kernel_launch(void* const* d_in, const int* in_sizes, int n_in,
                              void* d_out, int out_size, void* d_ws, size_t ws_size,
                              hipStream_t stream) {
  (void)in_sizes; (void)n_in; (void)out_size; (void)ws_size;
  const float* x      = (const float*)d_in[0];
  const float* w_qkv  = (const float*)d_in[1];
  const float* w_proj = (const float*)d_in[2];
  float* out = (float*)d_out;

  us* xb     = (us*)d_ws;            // 8192*1024
  us* wqkvT  = xb     + 8388608;     // 3072*1024
  us* wprojT = wqkvT  + 3145728;     // 1024*1024
  us* Qb     = wprojT + 1048576;     // [64][2048][64]
  us* Kb     = Qb     + 8388608;
  us* Vtb    = Kb     + 8388608;     // [64][64][2048]
  us* attn   = Vtb    + 8388608;     // [8192][1024]

  k_cvt<<<8192, 256, 0, stream>>>(x, xb, 8388608);
  k_tc<<<dim3(96, 32), dim3(32, 8), 0, stream>>>(w_qkv, wqkvT, 1024, 3072);
  k_tc<<<dim3(32, 32), dim3(32, 8), 0, stream>>>(w_proj, wprojT, 1024, 1024);
  k_gemm<1><<<dim3(24, 64), 256, 0, stream>>>(xb, wqkvT, nullptr, Qb, Kb, Vtb, 8192, 3072, 1024);
  k_attn<<<dim3(8, 64), 512, 0, stream>>>(Qb, Kb, Vtb, attn);
  k_gemm<0><<<dim3(8, 64), 256, 0, stream>>>(attn, wprojT, out, nullptr, nullptr, nullptr, 8192, 1024, 1024);
}